// Round 1
// 1085.751 us; speedup vs baseline: 1.0670x; 1.0670x over previous
//
#include <hip/hip_runtime.h>
#include <math.h>

#define DIMV 200
typedef unsigned short ushort;
typedef __attribute__((ext_vector_type(8))) __bf16  bf16x8;
typedef __attribute__((ext_vector_type(4))) float   f32x4;

static __device__ __forceinline__ int lower_bound(const int* __restrict__ a, int n, int key) {
    int lo = 0, hi = n;
    while (lo < hi) {
        int mid = (lo + hi) >> 1;
        if (a[mid] < key) lo = mid + 1; else hi = mid;
    }
    return lo;
}

static __device__ __forceinline__ float gate_fn(float u, float logit) {
    // bias = 1e-4: eps = (2b-1)*u + (1-b); sigmoid((log(eps)-log1p(-eps)+logit)/0.5)
    float ee = fmaf(u, -0.9998f, 0.9999f);
    float g  = (logf(ee) - log1pf(-ee) + logit) * 2.0f;
    return 1.0f / (1.0f + expf(-g));
}

static __device__ __forceinline__ ushort f2bf(float f) {
    unsigned int u = __float_as_uint(f);
    return (ushort)((u + 0x7fffu + ((u >> 16) & 1u)) >> 16);
}
static __device__ __forceinline__ float bf2f(ushort u) {
    return __uint_as_float(((unsigned int)u) << 16);
}

static __device__ __forceinline__ void cvt8_store(ushort* dst, const float* src) {
    float4 a = *(const float4*)src;
    float4 b = *(const float4*)(src + 4);
    dst[0] = f2bf(a.x); dst[1] = f2bf(a.y); dst[2] = f2bf(a.z); dst[3] = f2bf(a.w);
    dst[4] = f2bf(b.x); dst[5] = f2bf(b.y); dst[6] = f2bf(b.z); dst[7] = f2bf(b.w);
}
static __device__ __forceinline__ void zero8_store(ushort* dst) {
#pragma unroll
    for (int i = 0; i < 8; i++) dst[i] = 0;
}

// ---------------------------------------------------------------------------
// e0bf[n][0..223] = bf16(e0[n][k]) (zero-pad k>=200).  One 8-chunk per thread.
// ---------------------------------------------------------------------------
__global__ __launch_bounds__(256) void e0bf_kernel(
    const float* __restrict__ e0, ushort* __restrict__ e0bf, int N)
{
    int idx = blockIdx.x * 256 + threadIdx.x;   // chunk index: N*28
    if (idx >= N * 28) return;
    int n = idx / 28, c = idx % 28;
    ushort* dst = e0bf + (size_t)n * 224 + c * 8;
    if (c < 25) cvt8_store(dst, e0 + (size_t)n * 200 + c * 8);
    else        zero8_store(dst);
}

// ---------------------------------------------------------------------------
// Edge W1 combined transpose: B[k][n] = n<200 ? W1e[k][n] : W1e[k+200][n-200]
// dst[n][k] bf16, n<416, k<224 (zero pad)
// ---------------------------------------------------------------------------
__global__ __launch_bounds__(256) void transpose_w1e_kernel(
    const float* __restrict__ src, ushort* __restrict__ dst)
{
    int idx = blockIdx.x * 256 + threadIdx.x;
    if (idx >= 416 * 224) return;
    int n = idx / 224, k = idx % 224;
    float v = 0.f;
    if (k < 200) {
        if (n < 200)      v = src[k * 200 + n];
        else if (n < 400) v = src[(k + 200) * 200 + (n - 200)];
    }
    dst[idx] = f2bf(v);
}

// Node W1 transpose: dst[i][n][k] (208 x 224, zero-pad), src (i,200,200) k-major
__global__ __launch_bounds__(256) void transpose_w1n_kernel(
    const float* __restrict__ src, ushort* __restrict__ dst)
{
    int idx = blockIdx.x * 256 + threadIdx.x;
    int i = blockIdx.y;
    if (idx >= 208 * 224) return;
    int n = idx / 224, k = idx % 224;
    float v = (n < 200 && k < 200) ? src[i * 40000 + k * 200 + n] : 0.f;
    dst[(size_t)i * 208 * 224 + idx] = f2bf(v);
}

// rowptr[r] = lower_bound(row, E, r), r in [0, N]
__global__ __launch_bounds__(256) void rowptr_kernel(
    const int* __restrict__ row, int E, int N, int* __restrict__ rowptr)
{
    int r = blockIdx.x * 256 + threadIdx.x;
    if (r <= N) rowptr[r] = lower_bound(row, E, r);
}

// ---------------------------------------------------------------------------
// Plain GEMM: C[m][n] = sum_k A[m][k]*B[k][n], A = e0bf (M x 224 bf16),
// B^T = W1T (NTILES*208 x 224 bf16).  Block: 128m x 208n, grid (M/128, NTILES).
// C written BF16 (ushort) with row stride Cld, cols clipped to Nvalid.
// (P is only ever consumed by edge_gate; bf16 halves its gather traffic.)
// ---------------------------------------------------------------------------
__global__ __launch_bounds__(256) void gemm_e0_kernel(
    const ushort* __restrict__ e0bf, const ushort* __restrict__ W1T,
    ushort* __restrict__ C, int M, int Cld, int Nvalid)
{
    __shared__ __align__(16) ushort As[2][128 * 40];
    __shared__ __align__(16) ushort Bs[2][208 * 40];

    const int t    = threadIdx.x;
    const int lane = t & 63;
    const int w    = t >> 6;
    const int q    = lane >> 4;
    const int ln   = lane & 15;
    const int r0   = blockIdx.x * 128;
    const int nb   = blockIdx.y;               // 208-col tile
    const ushort* Wt = W1T + (size_t)nb * 208 * 224;

    f32x4 acc[2][13];
#pragma unroll
    for (int mt = 0; mt < 2; mt++)
#pragma unroll
        for (int nt = 0; nt < 13; nt++) {
            acc[mt][nt][0] = 0.f; acc[mt][nt][1] = 0.f;
            acc[mt][nt][2] = 0.f; acc[mt][nt][3] = 0.f;
        }

    auto stageA = [&](int ks, int buf) {
#pragma unroll
        for (int it = 0; it < 2; it++) {
            int f = t + it * 256;
            int m = f >> 2, c4 = f & 3;
            int g = r0 + m;
            ushort* dst = &As[buf][m * 40 + c4 * 8];
            if (g < M) *(bf16x8*)dst = *(const bf16x8*)&e0bf[(size_t)g * 224 + ks * 32 + c4 * 8];
            else       zero8_store(dst);
        }
    };
    auto stageB = [&](int ks, int buf) {
        for (int f = t; f < 832; f += 256) {
            int n = f >> 2, c4 = f & 3;
            *(bf16x8*)&Bs[buf][n * 40 + c4 * 8] =
                *(const bf16x8*)&Wt[(size_t)n * 224 + ks * 32 + c4 * 8];
        }
    };

    stageA(0, 0); stageB(0, 0);
    __syncthreads();

    for (int ks = 0; ks < 7; ks++) {
        int cur = ks & 1;
        if (ks + 1 < 7) { stageA(ks + 1, cur ^ 1); stageB(ks + 1, cur ^ 1); }
        bf16x8 af0 = *(const bf16x8*)&As[cur][(w * 32 + ln) * 40 + q * 8];
        bf16x8 af1 = *(const bf16x8*)&As[cur][(w * 32 + 16 + ln) * 40 + q * 8];
#pragma unroll
        for (int nt = 0; nt < 13; nt++) {
            bf16x8 bf = *(const bf16x8*)&Bs[cur][(nt * 16 + ln) * 40 + q * 8];
            acc[0][nt] = __builtin_amdgcn_mfma_f32_16x16x32_bf16(af0, bf, acc[0][nt], 0, 0, 0);
            acc[1][nt] = __builtin_amdgcn_mfma_f32_16x16x32_bf16(af1, bf, acc[1][nt], 0, 0, 0);
        }
        __syncthreads();
    }

#pragma unroll
    for (int mt = 0; mt < 2; mt++) {
        int gm = r0 + w * 32 + mt * 16 + q * 4;
#pragma unroll
        for (int nt = 0; nt < 13; nt++) {
            int gn = nb * 208 + nt * 16 + ln;
            if (gn < Nvalid) {
#pragma unroll
                for (int r = 0; r < 4; r++)
                    if (gm + r < M) C[(size_t)(gm + r) * Cld + gn] = f2bf(acc[mt][nt][r]);
            }
        }
    }
}

// ---------------------------------------------------------------------------
// Edge gate epilogue: logit_e = relu(P[row][d] + P[col][200+d] + b1[d]) . W2 + b2
// P stored bf16 (halved gather traffic).  One wave per contiguous edge chunk.
// ---------------------------------------------------------------------------
__global__ __launch_bounds__(256) void edge_gate_kernel(
    const ushort* __restrict__ P, const float* __restrict__ b1,
    const float* __restrict__ W2, const float* __restrict__ b2,
    const float* __restrict__ eps, const int* __restrict__ erow,
    const int* __restrict__ ecol, float* __restrict__ mask_out, int E)
{
    const int lane = threadIdx.x & 63;
    const int wave = (blockIdx.x * 256 + threadIdx.x) >> 6;
    const int nw   = gridDim.x * 4;
    const int chunk = (E + nw - 1) / nw;
    const int e_lo = wave * chunk;
    const int e_hi = min(e_lo + chunk, E);

    float bb[4], ww[4];
#pragma unroll
    for (int j = 0; j < 4; j++) {
        int d = lane + j * 64;
        bool v = d < 200;
        bb[j] = v ? b1[d] : 0.f;
        ww[j] = v ? W2[d] : 0.f;
    }
    const float b2v = b2[0];

    for (int e = e_lo; e < e_hi; e++) {
        const ushort* pr = P + (size_t)erow[e] * 400;
        const ushort* pc = P + (size_t)ecol[e] * 400 + 200;
        float s = 0.f;
#pragma unroll
        for (int j = 0; j < 4; j++) {
            int d = lane + j * 64;
            if (d < 200)
                s = fmaf(fmaxf(bf2f(pr[d]) + bf2f(pc[d]) + bb[j], 0.f), ww[j], s);
        }
#pragma unroll
        for (int off = 32; off; off >>= 1) s += __shfl_xor(s, off);
        if (lane == 0) mask_out[e] = gate_fn(eps[e], s + b2v);
    }
}

// ---------------------------------------------------------------------------
// Node MLP + gate via MFMA.  Block 128 rows x 208 hidden, K=224 (7 steps).
// A from e0bf (contiguous rows).  grid = (ceil(N/128), 2).
// ---------------------------------------------------------------------------
__global__ __launch_bounds__(256) void node_mlp_mfma(
    const ushort* __restrict__ e0bf,
    const ushort* __restrict__ W1T,  // [i][208][224]
    const float* __restrict__ b1, const float* __restrict__ W2,
    const float* __restrict__ b2, const float* __restrict__ eps,
    float* __restrict__ mask_out, int N)
{
    __shared__ __align__(16) ushort As[2][128 * 40];
    __shared__ __align__(16) ushort Bs[2][208 * 40];
    __shared__ float bsh[208], wsh[208];

    const int t    = threadIdx.x;
    const int lane = t & 63;
    const int w    = t >> 6;
    const int q    = lane >> 4;
    const int ln   = lane & 15;
    const int i    = blockIdx.y;
    const int r0   = blockIdx.x * 128;
    const ushort* Wt = W1T + (size_t)i * 208 * 224;

    if (t < 208) {
        bsh[t] = (t < 200) ? b1[i * 200 + t] : 0.f;
        wsh[t] = (t < 200) ? W2[i * 200 + t] : 0.f;
    }

    f32x4 acc[2][13];
#pragma unroll
    for (int mt = 0; mt < 2; mt++)
#pragma unroll
        for (int nt = 0; nt < 13; nt++) {
            acc[mt][nt][0] = 0.f; acc[mt][nt][1] = 0.f;
            acc[mt][nt][2] = 0.f; acc[mt][nt][3] = 0.f;
        }

    auto stageA = [&](int ks, int buf) {
#pragma unroll
        for (int it = 0; it < 2; it++) {
            int f = t + it * 256;
            int m = f >> 2, c4 = f & 3;
            int g = r0 + m;
            ushort* dst = &As[buf][m * 40 + c4 * 8];
            if (g < N) *(bf16x8*)dst = *(const bf16x8*)&e0bf[(size_t)g * 224 + ks * 32 + c4 * 8];
            else       zero8_store(dst);
        }
    };
    auto stageB = [&](int ks, int buf) {
        for (int f = t; f < 832; f += 256) {
            int n = f >> 2, c4 = f & 3;
            *(bf16x8*)&Bs[buf][n * 40 + c4 * 8] =
                *(const bf16x8*)&Wt[(size_t)n * 224 + ks * 32 + c4 * 8];
        }
    };

    stageA(0, 0); stageB(0, 0);
    __syncthreads();

    for (int ks = 0; ks < 7; ks++) {
        int cur = ks & 1;
        if (ks + 1 < 7) { stageA(ks + 1, cur ^ 1); stageB(ks + 1, cur ^ 1); }
        bf16x8 af0 = *(const bf16x8*)&As[cur][(w * 32 + ln) * 40 + q * 8];
        bf16x8 af1 = *(const bf16x8*)&As[cur][(w * 32 + 16 + ln) * 40 + q * 8];
#pragma unroll
        for (int nt = 0; nt < 13; nt++) {
            bf16x8 bf = *(const bf16x8*)&Bs[cur][(nt * 16 + ln) * 40 + q * 8];
            acc[0][nt] = __builtin_amdgcn_mfma_f32_16x16x32_bf16(af0, bf, acc[0][nt], 0, 0, 0);
            acc[1][nt] = __builtin_amdgcn_mfma_f32_16x16x32_bf16(af1, bf, acc[1][nt], 0, 0, 0);
        }
        __syncthreads();
    }

    float p[2][4];
#pragma unroll
    for (int mt = 0; mt < 2; mt++)
#pragma unroll
        for (int r = 0; r < 4; r++) {
            float s = 0.f;
#pragma unroll
            for (int nt = 0; nt < 13; nt++) {
                int n = nt * 16 + ln;
                float h = fmaxf(acc[mt][nt][r] + bsh[n], 0.f);
                s = fmaf(h, wsh[n], s);
            }
            p[mt][r] = s;
        }
#pragma unroll
    for (int off = 1; off < 16; off <<= 1)
#pragma unroll
        for (int mt = 0; mt < 2; mt++)
#pragma unroll
            for (int r = 0; r < 4; r++)
                p[mt][r] += __shfl_xor(p[mt][r], off);

    if (ln == 0) {
        float b2v = b2[i];
        const float* epsi = eps + (size_t)i * N;
        float* outi = mask_out + (size_t)i * N;
#pragma unroll
        for (int mt = 0; mt < 2; mt++)
#pragma unroll
            for (int r = 0; r < 4; r++) {
                int g = r0 + w * 32 + mt * 16 + q * 4 + r;
                if (g < N) outi[g] = gate_fn(epsi[g], p[mt][r] + b2v);
            }
    }
}

// ---------------------------------------------------------------------------
// scores = sigmoid(hr @ e0^T) via MFMA, A = hrbf, B = e0bf (pure copies).
// Block 64b x 192n, K=224 (7 steps), grid (ceil(N/192), 16).
// ---------------------------------------------------------------------------
__global__ __launch_bounds__(256) void scores_mfma(
    const ushort* __restrict__ hrbf, const ushort* __restrict__ e0bf,
    float* __restrict__ scores, int Nent)
{
    __shared__ __align__(16) ushort As[64 * 232];
    __shared__ __align__(16) ushort Bs[2][192 * 40];

    const int t    = threadIdx.x;
    const int lane = t & 63;
    const int w    = t >> 6;
    const int wm   = w >> 1, wn = w & 1;
    const int q    = lane >> 4;
    const int ln   = lane & 15;
    const int n0   = blockIdx.x * 192;
    const int b0   = blockIdx.y * 64;

    for (int f = t; f < 1792; f += 256) {
        int m = f / 28, c = f % 28;
        *(bf16x8*)&As[m * 232 + c * 8] = *(const bf16x8*)&hrbf[(size_t)(b0 + m) * 224 + c * 8];
    }

    auto stageB = [&](int ks, int buf) {
        for (int f = t; f < 768; f += 256) {
            int n = f >> 2, c4 = f & 3;
            int gn = n0 + n;
            ushort* dst = &Bs[buf][n * 40 + c4 * 8];
            if (gn < Nent) *(bf16x8*)dst = *(const bf16x8*)&e0bf[(size_t)gn * 224 + ks * 32 + c4 * 8];
            else           zero8_store(dst);
        }
    };
    stageB(0, 0);
    __syncthreads();

    f32x4 acc[2][6];
#pragma unroll
    for (int mt = 0; mt < 2; mt++)
#pragma unroll
        for (int nt = 0; nt < 6; nt++) {
            acc[mt][nt][0] = 0.f; acc[mt][nt][1] = 0.f;
            acc[mt][nt][2] = 0.f; acc[mt][nt][3] = 0.f;
        }

    for (int ks = 0; ks < 7; ks++) {
        int cur = ks & 1;
        if (ks + 1 < 7) stageB(ks + 1, cur ^ 1);
        bf16x8 af0 = *(const bf16x8*)&As[(wm * 32 + ln) * 232 + ks * 32 + q * 8];
        bf16x8 af1 = *(const bf16x8*)&As[(wm * 32 + 16 + ln) * 232 + ks * 32 + q * 8];
#pragma unroll
        for (int nt = 0; nt < 6; nt++) {
            bf16x8 bf = *(const bf16x8*)&Bs[cur][(wn * 96 + nt * 16 + ln) * 40 + q * 8];
            acc[0][nt] = __builtin_amdgcn_mfma_f32_16x16x32_bf16(af0, bf, acc[0][nt], 0, 0, 0);
            acc[1][nt] = __builtin_amdgcn_mfma_f32_16x16x32_bf16(af1, bf, acc[1][nt], 0, 0, 0);
        }
        __syncthreads();
    }

#pragma unroll
    for (int mt = 0; mt < 2; mt++) {
        int b = b0 + wm * 32 + mt * 16 + q * 4;
#pragma unroll
        for (int nt = 0; nt < 6; nt++) {
            int n = n0 + wn * 96 + nt * 16 + ln;
            if (n < Nent) {
#pragma unroll
                for (int r = 0; r < 4; r++)
                    scores[(size_t)(b + r) * Nent + n] = 1.f / (1.f + __expf(-acc[mt][nt][r]));
            }
        }
    }
}

// ---------------------------------------------------------------------------
// SpMM (CSR ranges via rowptr): out[r,:] = sum val*(emask?)*x[col[e],:]
// ---------------------------------------------------------------------------
__global__ __launch_bounds__(256) void spmm_kernel(
    const float* __restrict__ x, const int* __restrict__ rowptr,
    const int* __restrict__ col, const float* __restrict__ val,
    const float* __restrict__ emask, float* __restrict__ out)
{
    const int r = blockIdx.x;
    const int d = threadIdx.x;
    if (d >= DIMV) return;
    const int lo = rowptr[r], hi = rowptr[r + 1];
    float a0 = 0.f, a1 = 0.f;
    int e = lo;
    if (emask) {
        for (; e + 1 < hi; e += 2) {
            a0 = fmaf(val[e] * emask[e],         x[(size_t)col[e] * DIMV + d],     a0);
            a1 = fmaf(val[e + 1] * emask[e + 1], x[(size_t)col[e + 1] * DIMV + d], a1);
        }
        if (e < hi) a0 = fmaf(val[e] * emask[e], x[(size_t)col[e] * DIMV + d], a0);
    } else {
        for (; e + 1 < hi; e += 2) {
            a0 = fmaf(val[e],     x[(size_t)col[e] * DIMV + d],     a0);
            a1 = fmaf(val[e + 1], x[(size_t)col[e + 1] * DIMV + d], a1);
        }
        if (e < hi) a0 = fmaf(val[e], x[(size_t)col[e] * DIMV + d], a0);
    }
    out[(size_t)r * DIMV + d] = a0 + a1;
}

// ---------------------------------------------------------------------------
// Dual SpMM over the SAME sparsity (adj):
//   outA[r,:] = sum val*emask * xA[col,:]   (edge-drop masked propagate)
//   outB[r,:] = sum val        * xB[col,:]  (node-branch first adj hop)
// Amortizes rowptr/col/val/loop overhead across both gathers.
// ---------------------------------------------------------------------------
__global__ __launch_bounds__(256) void spmm_dual_kernel(
    const float* __restrict__ xA, const float* __restrict__ xB,
    const int* __restrict__ rowptr, const int* __restrict__ col,
    const float* __restrict__ val, const float* __restrict__ emask,
    float* __restrict__ outA, float* __restrict__ outB)
{
    const int r = blockIdx.x;
    const int d = threadIdx.x;
    if (d >= DIMV) return;
    const int lo = rowptr[r], hi = rowptr[r + 1];
    float a0 = 0.f, a1 = 0.f, b0 = 0.f, b1 = 0.f;
    int e = lo;
    for (; e + 1 < hi; e += 2) {
        size_t o0 = (size_t)col[e] * DIMV + d;
        size_t o1 = (size_t)col[e + 1] * DIMV + d;
        float v0 = val[e], v1 = val[e + 1];
        a0 = fmaf(v0 * emask[e],     xA[o0], a0);
        a1 = fmaf(v1 * emask[e + 1], xA[o1], a1);
        b0 = fmaf(v0, xB[o0], b0);
        b1 = fmaf(v1, xB[o1], b1);
    }
    if (e < hi) {
        size_t o0 = (size_t)col[e] * DIMV + d;
        a0 = fmaf(val[e] * emask[e], xA[o0], a0);
        b0 = fmaf(val[e], xB[o0], b0);
    }
    outA[(size_t)r * DIMV + d] = a0 + a1;
    outB[(size_t)r * DIMV + d] = b0 + b1;
}

// out = m[row]*x + (1-m[row])*mp   (element-wise, float4 over N*200)
__global__ __launch_bounds__(256) void combine_kernel(
    const float* __restrict__ x, const float* __restrict__ mp,
    const float* __restrict__ mask, float* __restrict__ out, int N)
{
    int idx = blockIdx.x * 256 + threadIdx.x;   // float4 index over N*50
    if (idx >= N * 50) return;
    float m = mask[idx / 50];
    float4 a = ((const float4*)x)[idx];
    float4 b = ((const float4*)mp)[idx];
    float4 o;
    o.x = fmaf(m, a.x - b.x, b.x);
    o.y = fmaf(m, a.y - b.y, b.y);
    o.z = fmaf(m, a.z - b.z, b.z);
    o.w = fmaf(m, a.w - b.w, b.w);
    ((float4*)out)[idx] = o;
}

__global__ __launch_bounds__(256) void rw_combine_kernel(
    const float* __restrict__ x, const int* __restrict__ rowptr,
    const int* __restrict__ col, const float* __restrict__ val,
    const float* __restrict__ mask, float* __restrict__ out)
{
    const int r = blockIdx.x;
    const int d = threadIdx.x;
    if (d >= DIMV) return;
    const int lo = rowptr[r], hi = rowptr[r + 1];
    float a0 = 0.f, a1 = 0.f;
    int e = lo;
    for (; e + 1 < hi; e += 2) {
        a0 = fmaf(val[e],     x[(size_t)col[e] * DIMV + d],     a0);
        a1 = fmaf(val[e + 1], x[(size_t)col[e + 1] * DIMV + d], a1);
    }
    if (e < hi) a0 = fmaf(val[e], x[(size_t)col[e] * DIMV + d], a0);
    const float m = mask[r];
    out[(size_t)r * DIMV + d] = m * x[(size_t)r * DIMV + d] + (1.f - m) * (a0 + a1);
}

// self_hr -> bf16 (stride 224, zero-padded)
__global__ __launch_bounds__(256) void selfhr_kernel(
    const float* __restrict__ e0, const float* __restrict__ rel_emb,
    const int* __restrict__ sub, const int* __restrict__ rel,
    ushort* __restrict__ hrbf)
{
    const int b = blockIdx.x;
    __shared__ float lhs[DIMV];
    const int t = threadIdx.x;
    if (t < DIMV) lhs[t] = e0[(size_t)sub[b] * DIMV + t];
    __syncthreads();
    if (t >= 224) return;
    if (t < DIMV) {
        const float* R = rel_emb + (size_t)rel[b] * (DIMV * DIMV);
        float acc = 0.f;
        for (int dd = 0; dd < DIMV; dd++)
            acc = fmaf(lhs[dd], R[dd * DIMV + t], acc);
        hrbf[(size_t)b * 224 + t] = f2bf(acc);
    } else {
        hrbf[(size_t)b * 224 + t] = 0;
    }
}

extern "C" void kernel_launch(void* const* d_in, const int* in_sizes, int n_in,
                              void* d_out, int out_size, void* d_ws, size_t ws_size,
                              hipStream_t stream)
{
    const float* e0       = (const float*)d_in[0];
    const float* rel_emb  = (const float*)d_in[1];
    const float* node_W1  = (const float*)d_in[2];
    const float* node_b1  = (const float*)d_in[3];
    const float* node_W2  = (const float*)d_in[4];
    const float* node_b2  = (const float*)d_in[5];
    const float* edge_W1  = (const float*)d_in[6];
    const float* edge_b1  = (const float*)d_in[7];
    const float* edge_W2  = (const float*)d_in[8];
    const float* edge_b2  = (const float*)d_in[9];
    const int*   adj_row  = (const int*)d_in[10];
    const int*   adj_col  = (const int*)d_in[11];
    const float* adj_val  = (const float*)d_in[12];
    const int*   rw_row   = (const int*)d_in[13];
    const int*   rw_col   = (const int*)d_in[14];
    const float* rw_val   = (const float*)d_in[15];
    const float* node_eps = (const float*)d_in[16];
    const float* edge_eps = (const float*)d_in[17];
    const int*   sub      = (const int*)d_in[18];
    const int*   rel      = (const int*)d_in[19];

    const int E   = in_sizes[10];
    const int Erw = in_sizes[13];
    const int N   = in_sizes[0] / DIMV;   // 50000
    const int B   = in_sizes[18];         // 1024

    // workspace layout (~25.6 MB)
    ushort* W1eT = (ushort*)d_ws;                      // 416*224
    ushort* W1nT = W1eT + 416 * 224;                   // 2*208*224
    ushort* e0bf = W1nT + 2 * 208 * 224;               // N*224
    ushort* hrbf = e0bf + (size_t)N * 224;             // B*224
    float*  fb   = (float*)(hrbf + (size_t)B * 224);
    float*  node_mask = fb;                            // 2*N
    float*  edge_mask = node_mask + 2 * (size_t)N;     // E
    int*    rp_adj = (int*)(edge_mask + E);            // N+1
    int*    rp_rw  = rp_adj + (N + 1);                 // N+1

    // output layout: scores (B*N), x_nd (N*200), x_ed (N*200)
    float* out    = (float*)d_out;
    float* scores = out;
    float* x_nd   = out + (size_t)B * N;
    float* x_ed   = x_nd + (size_t)N * DIMV;
    // scores region as scratch until the final GEMM:
    float*  T  = scores;                               // N*200 f32
    float*  T2 = scores + (size_t)N * DIMV;            // N*200 f32
    ushort* Pb = (ushort*)(scores + 2 * (size_t)N * DIMV);  // N*400 bf16 (edge hidden)

    // 0. preps
    e0bf_kernel<<<(N * 28 + 255) / 256, 256, 0, stream>>>(e0, e0bf, N);
    transpose_w1e_kernel<<<(416 * 224 + 255) / 256, 256, 0, stream>>>(edge_W1 + 400 * 200, W1eT);
    transpose_w1n_kernel<<<dim3((208 * 224 + 255) / 256, 2), 256, 0, stream>>>(node_W1, W1nT);
    rowptr_kernel<<<(N + 256) / 256, 256, 0, stream>>>(adj_row, E,   N, rp_adj);
    rowptr_kernel<<<(N + 256) / 256, 256, 0, stream>>>(rw_row,  Erw, N, rp_rw);

    // 1. edge path: Pb = bf16(e0 @ [W1a|W1b]) (node-level), then per-edge gate
    gemm_e0_kernel<<<dim3((N + 127) / 128, 2), 256, 0, stream>>>(e0bf, W1eT, Pb, N, 400, 400);
    edge_gate_kernel<<<6144, 256, 0, stream>>>(
        Pb, edge_b1 + 200, edge_W2 + 200, edge_b2 + 1, edge_eps + (size_t)E,
        adj_row, adj_col, edge_mask, E);

    // 2. node masks (both i)
    node_mlp_mfma<<<dim3((N + 127) / 128, 2), 256, 0, stream>>>(
        e0bf, W1nT, node_b1, node_W2, node_b2, node_eps, node_mask, N);

    // 3. shared first rw hop: T = rw(e0) — used by BOTH branches (was computed twice)
    spmm_kernel<<<N, 256, 0, stream>>>(e0, rp_rw, rw_col, rw_val, nullptr, T);

    // 4. edge branch second hop: T2 = rw(T)
    spmm_kernel<<<N, 256, 0, stream>>>(T, rp_rw, rw_col, rw_val, nullptr, T2);

    // 5. node branch step 1 (cheap elementwise, reuses T): x_nd = m0*e0 + (1-m0)*T
    combine_kernel<<<(N * 50 + 255) / 256, 256, 0, stream>>>(e0, T, node_mask, x_nd, N);

    // 6. dual adj propagate: x_ed = adj_masked(T2); T = adj(x_nd)
    spmm_dual_kernel<<<N, 256, 0, stream>>>(T2, x_nd, rp_adj, adj_col, adj_val,
                                            edge_mask, x_ed, T);

    // 7. node branch: T2 = m1*T + (1-m1)*rw(T); x_nd = adj(T2)
    rw_combine_kernel<<<N, 256, 0, stream>>>(T, rp_rw, rw_col, rw_val, node_mask + N, T2);
    spmm_kernel      <<<N, 256, 0, stream>>>(T2, rp_adj, adj_col, adj_val, nullptr, x_nd);

    // 8. self_hr -> bf16
    selfhr_kernel<<<B, 256, 0, stream>>>(e0, rel_emb, sub, rel, hrbf);

    // 9. scores = sigmoid(self_hr @ e0^T) via MFMA
    scores_mfma<<<dim3((N + 191) / 192, B / 64), 256, 0, stream>>>(hrbf, e0bf, scores, N);
}

// Round 2
// 978.077 us; speedup vs baseline: 1.1845x; 1.1101x over previous
//
#include <hip/hip_runtime.h>
#include <math.h>

#define DIMV 200
typedef unsigned short ushort;
typedef unsigned int uint;
typedef __attribute__((ext_vector_type(8))) __bf16  bf16x8;
typedef __attribute__((ext_vector_type(4))) float   f32x4;

static __device__ __forceinline__ int lower_bound(const int* __restrict__ a, int n, int key) {
    int lo = 0, hi = n;
    while (lo < hi) {
        int mid = (lo + hi) >> 1;
        if (a[mid] < key) lo = mid + 1; else hi = mid;
    }
    return lo;
}

static __device__ __forceinline__ float gate_fn(float u, float logit) {
    // bias = 1e-4: eps = (2b-1)*u + (1-b); sigmoid((log(eps)-log1p(-eps)+logit)/0.5)
    float ee = fmaf(u, -0.9998f, 0.9999f);
    float g  = (logf(ee) - log1pf(-ee) + logit) * 2.0f;
    return 1.0f / (1.0f + expf(-g));
}

static __device__ __forceinline__ ushort f2bf(float f) {
    unsigned int u = __float_as_uint(f);
    return (ushort)((u + 0x7fffu + ((u >> 16) & 1u)) >> 16);
}
static __device__ __forceinline__ float bf2f(ushort u) {
    return __uint_as_float(((unsigned int)u) << 16);
}
// packed pair: low ushort = dim 2k, high ushort = dim 2k+1
static __device__ __forceinline__ float2 bfp2f(uint u) {
    float2 r;
    r.x = __uint_as_float(u << 16);
    r.y = __uint_as_float(u & 0xffff0000u);
    return r;
}
static __device__ __forceinline__ uint f2bfp(float a, float b) {
    return (uint)f2bf(a) | ((uint)f2bf(b) << 16);
}

static __device__ __forceinline__ void cvt8_store(ushort* dst, const float* src) {
    float4 a = *(const float4*)src;
    float4 b = *(const float4*)(src + 4);
    dst[0] = f2bf(a.x); dst[1] = f2bf(a.y); dst[2] = f2bf(a.z); dst[3] = f2bf(a.w);
    dst[4] = f2bf(b.x); dst[5] = f2bf(b.y); dst[6] = f2bf(b.z); dst[7] = f2bf(b.w);
}
static __device__ __forceinline__ void zero8_store(ushort* dst) {
#pragma unroll
    for (int i = 0; i < 8; i++) dst[i] = 0;
}

// ---------------------------------------------------------------------------
// e0bf[n][0..223] = bf16(e0[n][k]) (zero-pad k>=200).  One 8-chunk per thread.
// ---------------------------------------------------------------------------
__global__ __launch_bounds__(256) void e0bf_kernel(
    const float* __restrict__ e0, ushort* __restrict__ e0bf, int N)
{
    int idx = blockIdx.x * 256 + threadIdx.x;   // chunk index: N*28
    if (idx >= N * 28) return;
    int n = idx / 28, c = idx % 28;
    ushort* dst = e0bf + (size_t)n * 224 + c * 8;
    if (c < 25) cvt8_store(dst, e0 + (size_t)n * 200 + c * 8);
    else        zero8_store(dst);
}

// ---------------------------------------------------------------------------
// Edge W1 combined transpose: B[k][n] = n<200 ? W1e[k][n] : W1e[k+200][n-200]
// dst[n][k] bf16, n<416, k<224 (zero pad)
// ---------------------------------------------------------------------------
__global__ __launch_bounds__(256) void transpose_w1e_kernel(
    const float* __restrict__ src, ushort* __restrict__ dst)
{
    int idx = blockIdx.x * 256 + threadIdx.x;
    if (idx >= 416 * 224) return;
    int n = idx / 224, k = idx % 224;
    float v = 0.f;
    if (k < 200) {
        if (n < 200)      v = src[k * 200 + n];
        else if (n < 400) v = src[(k + 200) * 200 + (n - 200)];
    }
    dst[idx] = f2bf(v);
}

// Node W1 transpose: dst[i][n][k] (208 x 224, zero-pad), src (i,200,200) k-major
__global__ __launch_bounds__(256) void transpose_w1n_kernel(
    const float* __restrict__ src, ushort* __restrict__ dst)
{
    int idx = blockIdx.x * 256 + threadIdx.x;
    int i = blockIdx.y;
    if (idx >= 208 * 224) return;
    int n = idx / 224, k = idx % 224;
    float v = (n < 200 && k < 200) ? src[i * 40000 + k * 200 + n] : 0.f;
    dst[(size_t)i * 208 * 224 + idx] = f2bf(v);
}

// rowptr[r] = lower_bound(row, E, r), r in [0, N]
__global__ __launch_bounds__(256) void rowptr_kernel(
    const int* __restrict__ row, int E, int N, int* __restrict__ rowptr)
{
    int r = blockIdx.x * 256 + threadIdx.x;
    if (r <= N) rowptr[r] = lower_bound(row, E, r);
}

// ---------------------------------------------------------------------------
// Plain GEMM: C[m][n] = sum_k A[m][k]*B[k][n], A = e0bf (M x 224 bf16),
// B^T = W1T (NTILES*208 x 224 bf16).  Block: 128m x 208n, grid (M/128, NTILES).
// C written BF16 (ushort) with row stride Cld, cols clipped to Nvalid.
// ---------------------------------------------------------------------------
__global__ __launch_bounds__(256) void gemm_e0_kernel(
    const ushort* __restrict__ e0bf, const ushort* __restrict__ W1T,
    ushort* __restrict__ C, int M, int Cld, int Nvalid)
{
    __shared__ __align__(16) ushort As[2][128 * 40];
    __shared__ __align__(16) ushort Bs[2][208 * 40];

    const int t    = threadIdx.x;
    const int lane = t & 63;
    const int w    = t >> 6;
    const int q    = lane >> 4;
    const int ln   = lane & 15;
    const int r0   = blockIdx.x * 128;
    const int nb   = blockIdx.y;               // 208-col tile
    const ushort* Wt = W1T + (size_t)nb * 208 * 224;

    f32x4 acc[2][13];
#pragma unroll
    for (int mt = 0; mt < 2; mt++)
#pragma unroll
        for (int nt = 0; nt < 13; nt++) {
            acc[mt][nt][0] = 0.f; acc[mt][nt][1] = 0.f;
            acc[mt][nt][2] = 0.f; acc[mt][nt][3] = 0.f;
        }

    auto stageA = [&](int ks, int buf) {
#pragma unroll
        for (int it = 0; it < 2; it++) {
            int f = t + it * 256;
            int m = f >> 2, c4 = f & 3;
            int g = r0 + m;
            ushort* dst = &As[buf][m * 40 + c4 * 8];
            if (g < M) *(bf16x8*)dst = *(const bf16x8*)&e0bf[(size_t)g * 224 + ks * 32 + c4 * 8];
            else       zero8_store(dst);
        }
    };
    auto stageB = [&](int ks, int buf) {
        for (int f = t; f < 832; f += 256) {
            int n = f >> 2, c4 = f & 3;
            *(bf16x8*)&Bs[buf][n * 40 + c4 * 8] =
                *(const bf16x8*)&Wt[(size_t)n * 224 + ks * 32 + c4 * 8];
        }
    };

    stageA(0, 0); stageB(0, 0);
    __syncthreads();

    for (int ks = 0; ks < 7; ks++) {
        int cur = ks & 1;
        if (ks + 1 < 7) { stageA(ks + 1, cur ^ 1); stageB(ks + 1, cur ^ 1); }
        bf16x8 af0 = *(const bf16x8*)&As[cur][(w * 32 + ln) * 40 + q * 8];
        bf16x8 af1 = *(const bf16x8*)&As[cur][(w * 32 + 16 + ln) * 40 + q * 8];
#pragma unroll
        for (int nt = 0; nt < 13; nt++) {
            bf16x8 bf = *(const bf16x8*)&Bs[cur][(nt * 16 + ln) * 40 + q * 8];
            acc[0][nt] = __builtin_amdgcn_mfma_f32_16x16x32_bf16(af0, bf, acc[0][nt], 0, 0, 0);
            acc[1][nt] = __builtin_amdgcn_mfma_f32_16x16x32_bf16(af1, bf, acc[1][nt], 0, 0, 0);
        }
        __syncthreads();
    }

#pragma unroll
    for (int mt = 0; mt < 2; mt++) {
        int gm = r0 + w * 32 + mt * 16 + q * 4;
#pragma unroll
        for (int nt = 0; nt < 13; nt++) {
            int gn = nb * 208 + nt * 16 + ln;
            if (gn < Nvalid) {
#pragma unroll
                for (int r = 0; r < 4; r++)
                    if (gm + r < M) C[(size_t)(gm + r) * Cld + gn] = f2bf(acc[mt][nt][r]);
            }
        }
    }
}

// ---------------------------------------------------------------------------
// Edge gate epilogue: logit_e = relu(P[row][d] + P[col][200+d] + b1[d]) . W2 + b2
// P stored bf16.  One wave per contiguous edge chunk (row-sorted edges).
// ---------------------------------------------------------------------------
__global__ __launch_bounds__(256) void edge_gate_kernel(
    const ushort* __restrict__ P, const float* __restrict__ b1,
    const float* __restrict__ W2, const float* __restrict__ b2,
    const float* __restrict__ eps, const int* __restrict__ erow,
    const int* __restrict__ ecol, float* __restrict__ mask_out, int E)
{
    const int lane = threadIdx.x & 63;
    const int wave = (blockIdx.x * 256 + threadIdx.x) >> 6;
    const int nw   = gridDim.x * 4;
    const int chunk = (E + nw - 1) / nw;
    const int e_lo = wave * chunk;
    const int e_hi = min(e_lo + chunk, E);

    float bb[4], ww[4];
#pragma unroll
    for (int j = 0; j < 4; j++) {
        int d = lane + j * 64;
        bool v = d < 200;
        bb[j] = v ? b1[d] : 0.f;
        ww[j] = v ? W2[d] : 0.f;
    }
    const float b2v = b2[0];

    for (int e = e_lo; e < e_hi; e++) {
        const ushort* pr = P + (size_t)erow[e] * 400;
        const ushort* pc = P + (size_t)ecol[e] * 400 + 200;
        float s = 0.f;
#pragma unroll
        for (int j = 0; j < 4; j++) {
            int d = lane + j * 64;
            if (d < 200)
                s = fmaf(fmaxf(bf2f(pr[d]) + bf2f(pc[d]) + bb[j], 0.f), ww[j], s);
        }
#pragma unroll
        for (int off = 32; off; off >>= 1) s += __shfl_xor(s, off);
        if (lane == 0) mask_out[e] = gate_fn(eps[e], s + b2v);
    }
}

// ---------------------------------------------------------------------------
// Node MLP + gate via MFMA.  Block 128 rows x 208 hidden, K=224 (7 steps).
// ---------------------------------------------------------------------------
__global__ __launch_bounds__(256) void node_mlp_mfma(
    const ushort* __restrict__ e0bf,
    const ushort* __restrict__ W1T,  // [i][208][224]
    const float* __restrict__ b1, const float* __restrict__ W2,
    const float* __restrict__ b2, const float* __restrict__ eps,
    float* __restrict__ mask_out, int N)
{
    __shared__ __align__(16) ushort As[2][128 * 40];
    __shared__ __align__(16) ushort Bs[2][208 * 40];
    __shared__ float bsh[208], wsh[208];

    const int t    = threadIdx.x;
    const int lane = t & 63;
    const int w    = t >> 6;
    const int q    = lane >> 4;
    const int ln   = lane & 15;
    const int i    = blockIdx.y;
    const int r0   = blockIdx.x * 128;
    const ushort* Wt = W1T + (size_t)i * 208 * 224;

    if (t < 208) {
        bsh[t] = (t < 200) ? b1[i * 200 + t] : 0.f;
        wsh[t] = (t < 200) ? W2[i * 200 + t] : 0.f;
    }

    f32x4 acc[2][13];
#pragma unroll
    for (int mt = 0; mt < 2; mt++)
#pragma unroll
        for (int nt = 0; nt < 13; nt++) {
            acc[mt][nt][0] = 0.f; acc[mt][nt][1] = 0.f;
            acc[mt][nt][2] = 0.f; acc[mt][nt][3] = 0.f;
        }

    auto stageA = [&](int ks, int buf) {
#pragma unroll
        for (int it = 0; it < 2; it++) {
            int f = t + it * 256;
            int m = f >> 2, c4 = f & 3;
            int g = r0 + m;
            ushort* dst = &As[buf][m * 40 + c4 * 8];
            if (g < N) *(bf16x8*)dst = *(const bf16x8*)&e0bf[(size_t)g * 224 + ks * 32 + c4 * 8];
            else       zero8_store(dst);
        }
    };
    auto stageB = [&](int ks, int buf) {
        for (int f = t; f < 832; f += 256) {
            int n = f >> 2, c4 = f & 3;
            *(bf16x8*)&Bs[buf][n * 40 + c4 * 8] =
                *(const bf16x8*)&Wt[(size_t)n * 224 + ks * 32 + c4 * 8];
        }
    };

    stageA(0, 0); stageB(0, 0);
    __syncthreads();

    for (int ks = 0; ks < 7; ks++) {
        int cur = ks & 1;
        if (ks + 1 < 7) { stageA(ks + 1, cur ^ 1); stageB(ks + 1, cur ^ 1); }
        bf16x8 af0 = *(const bf16x8*)&As[cur][(w * 32 + ln) * 40 + q * 8];
        bf16x8 af1 = *(const bf16x8*)&As[cur][(w * 32 + 16 + ln) * 40 + q * 8];
#pragma unroll
        for (int nt = 0; nt < 13; nt++) {
            bf16x8 bf = *(const bf16x8*)&Bs[cur][(nt * 16 + ln) * 40 + q * 8];
            acc[0][nt] = __builtin_amdgcn_mfma_f32_16x16x32_bf16(af0, bf, acc[0][nt], 0, 0, 0);
            acc[1][nt] = __builtin_amdgcn_mfma_f32_16x16x32_bf16(af1, bf, acc[1][nt], 0, 0, 0);
        }
        __syncthreads();
    }

    float p[2][4];
#pragma unroll
    for (int mt = 0; mt < 2; mt++)
#pragma unroll
        for (int r = 0; r < 4; r++) {
            float s = 0.f;
#pragma unroll
            for (int nt = 0; nt < 13; nt++) {
                int n = nt * 16 + ln;
                float h = fmaxf(acc[mt][nt][r] + bsh[n], 0.f);
                s = fmaf(h, wsh[n], s);
            }
            p[mt][r] = s;
        }
#pragma unroll
    for (int off = 1; off < 16; off <<= 1)
#pragma unroll
        for (int mt = 0; mt < 2; mt++)
#pragma unroll
            for (int r = 0; r < 4; r++)
                p[mt][r] += __shfl_xor(p[mt][r], off);

    if (ln == 0) {
        float b2v = b2[i];
        const float* epsi = eps + (size_t)i * N;
        float* outi = mask_out + (size_t)i * N;
#pragma unroll
        for (int mt = 0; mt < 2; mt++)
#pragma unroll
            for (int r = 0; r < 4; r++) {
                int g = r0 + w * 32 + mt * 16 + q * 4 + r;
                if (g < N) outi[g] = gate_fn(epsi[g], p[mt][r] + b2v);
            }
    }
}

// ---------------------------------------------------------------------------
// scores = sigmoid(hr @ e0^T) via MFMA.
// ---------------------------------------------------------------------------
__global__ __launch_bounds__(256) void scores_mfma(
    const ushort* __restrict__ hrbf, const ushort* __restrict__ e0bf,
    float* __restrict__ scores, int Nent)
{
    __shared__ __align__(16) ushort As[64 * 232];
    __shared__ __align__(16) ushort Bs[2][192 * 40];

    const int t    = threadIdx.x;
    const int lane = t & 63;
    const int w    = t >> 6;
    const int wm   = w >> 1, wn = w & 1;
    const int q    = lane >> 4;
    const int ln   = lane & 15;
    const int n0   = blockIdx.x * 192;
    const int b0   = blockIdx.y * 64;

    for (int f = t; f < 1792; f += 256) {
        int m = f / 28, c = f % 28;
        *(bf16x8*)&As[m * 232 + c * 8] = *(const bf16x8*)&hrbf[(size_t)(b0 + m) * 224 + c * 8];
    }

    auto stageB = [&](int ks, int buf) {
        for (int f = t; f < 768; f += 256) {
            int n = f >> 2, c4 = f & 3;
            int gn = n0 + n;
            ushort* dst = &Bs[buf][n * 40 + c4 * 8];
            if (gn < Nent) *(bf16x8*)dst = *(const bf16x8*)&e0bf[(size_t)gn * 224 + ks * 32 + c4 * 8];
            else           zero8_store(dst);
        }
    };
    stageB(0, 0);
    __syncthreads();

    f32x4 acc[2][6];
#pragma unroll
    for (int mt = 0; mt < 2; mt++)
#pragma unroll
        for (int nt = 0; nt < 6; nt++) {
            acc[mt][nt][0] = 0.f; acc[mt][nt][1] = 0.f;
            acc[mt][nt][2] = 0.f; acc[mt][nt][3] = 0.f;
        }

    for (int ks = 0; ks < 7; ks++) {
        int cur = ks & 1;
        if (ks + 1 < 7) stageB(ks + 1, cur ^ 1);
        bf16x8 af0 = *(const bf16x8*)&As[(wm * 32 + ln) * 232 + ks * 32 + q * 8];
        bf16x8 af1 = *(const bf16x8*)&As[(wm * 32 + 16 + ln) * 232 + ks * 32 + q * 8];
#pragma unroll
        for (int nt = 0; nt < 6; nt++) {
            bf16x8 bf = *(const bf16x8*)&Bs[cur][(wn * 96 + nt * 16 + ln) * 40 + q * 8];
            acc[0][nt] = __builtin_amdgcn_mfma_f32_16x16x32_bf16(af0, bf, acc[0][nt], 0, 0, 0);
            acc[1][nt] = __builtin_amdgcn_mfma_f32_16x16x32_bf16(af1, bf, acc[1][nt], 0, 0, 0);
        }
        __syncthreads();
    }

#pragma unroll
    for (int mt = 0; mt < 2; mt++) {
        int b = b0 + wm * 32 + mt * 16 + q * 4;
#pragma unroll
        for (int nt = 0; nt < 6; nt++) {
            int n = n0 + wn * 96 + nt * 16 + ln;
            if (n < Nent) {
#pragma unroll
                for (int r = 0; r < 4; r++)
                    scores[(size_t)(b + r) * Nent + n] = 1.f / (1.f + __expf(-acc[mt][nt][r]));
            }
        }
    }
}

// ===========================================================================
// Packed-bf16 sparse chain.  Rows are 100 uints (= 200 bf16).  2 rows/block,
// 128 threads per row, 100 active, each handling dims [2*d2, 2*d2+1].
// Accumulation in f32; only inter-pass storage is bf16.
// ===========================================================================

// out(bf16) = spmm(x bf16 stride xld uints)
__global__ __launch_bounds__(256) void spmm_bb(
    const uint* __restrict__ x, int xld, const int* __restrict__ rowptr,
    const int* __restrict__ col, const float* __restrict__ val,
    uint* __restrict__ out, int N)
{
    const int sub = threadIdx.x >> 7;
    const int d2  = threadIdx.x & 127;
    const int r   = blockIdx.x * 2 + sub;
    if (d2 >= 100 || r >= N) return;
    const int lo = rowptr[r], hi = rowptr[r + 1];
    float a0 = 0.f, a1 = 0.f, b0 = 0.f, b1 = 0.f;
    int e = lo;
    for (; e + 1 < hi; e += 2) {
        float2 xa = bfp2f(x[(size_t)col[e]     * xld + d2]);
        float2 xb = bfp2f(x[(size_t)col[e + 1] * xld + d2]);
        float v0 = val[e], v1 = val[e + 1];
        a0 = fmaf(v0, xa.x, a0); b0 = fmaf(v0, xa.y, b0);
        a1 = fmaf(v1, xb.x, a1); b1 = fmaf(v1, xb.y, b1);
    }
    if (e < hi) {
        float2 xa = bfp2f(x[(size_t)col[e] * xld + d2]);
        a0 = fmaf(val[e], xa.x, a0); b0 = fmaf(val[e], xa.y, b0);
    }
    out[(size_t)r * 100 + d2] = f2bfp(a0 + a1, b0 + b1);
}

// out(bf16) = m[r]*x[r] + (1-m[r])*spmm(x)   (x bf16 stride 100)
__global__ __launch_bounds__(256) void rw_combine_bb(
    const uint* __restrict__ x, const int* __restrict__ rowptr,
    const int* __restrict__ col, const float* __restrict__ val,
    const float* __restrict__ mask, uint* __restrict__ out, int N)
{
    const int sub = threadIdx.x >> 7;
    const int d2  = threadIdx.x & 127;
    const int r   = blockIdx.x * 2 + sub;
    if (d2 >= 100 || r >= N) return;
    const int lo = rowptr[r], hi = rowptr[r + 1];
    float a0 = 0.f, a1 = 0.f, b0 = 0.f, b1 = 0.f;
    int e = lo;
    for (; e + 1 < hi; e += 2) {
        float2 xa = bfp2f(x[(size_t)col[e]     * 100 + d2]);
        float2 xb = bfp2f(x[(size_t)col[e + 1] * 100 + d2]);
        float v0 = val[e], v1 = val[e + 1];
        a0 = fmaf(v0, xa.x, a0); b0 = fmaf(v0, xa.y, b0);
        a1 = fmaf(v1, xb.x, a1); b1 = fmaf(v1, xb.y, b1);
    }
    if (e < hi) {
        float2 xa = bfp2f(x[(size_t)col[e] * 100 + d2]);
        a0 = fmaf(val[e], xa.x, a0); b0 = fmaf(val[e], xa.y, b0);
    }
    const float m = mask[r];
    float2 xs = bfp2f(x[(size_t)r * 100 + d2]);
    float sx = a0 + a1, sy = b0 + b1;
    out[(size_t)r * 100 + d2] = f2bfp(fmaf(m, xs.x - sx, sx), fmaf(m, xs.y - sy, sy));
}

// Dual adj pass over same sparsity:
//   outA(f32, final x_ed) = sum val*emask * xA[col]
//   outB(bf16)            = sum val        * xB[col]
__global__ __launch_bounds__(256) void spmm_dual_bb(
    const uint* __restrict__ xA, const uint* __restrict__ xB,
    const int* __restrict__ rowptr, const int* __restrict__ col,
    const float* __restrict__ val, const float* __restrict__ emask,
    float* __restrict__ outA, uint* __restrict__ outB, int N)
{
    const int sub = threadIdx.x >> 7;
    const int d2  = threadIdx.x & 127;
    const int r   = blockIdx.x * 2 + sub;
    if (d2 >= 100 || r >= N) return;
    const int lo = rowptr[r], hi = rowptr[r + 1];
    float a0 = 0.f, a1 = 0.f, b0 = 0.f, b1 = 0.f;
    float c0 = 0.f, c1 = 0.f, d0 = 0.f, d1 = 0.f;
    int e = lo;
    for (; e + 1 < hi; e += 2) {
        size_t o0 = (size_t)col[e]     * 100 + d2;
        size_t o1 = (size_t)col[e + 1] * 100 + d2;
        float v0 = val[e], v1 = val[e + 1];
        float vm0 = v0 * emask[e], vm1 = v1 * emask[e + 1];
        float2 xa0 = bfp2f(xA[o0]), xa1 = bfp2f(xA[o1]);
        float2 xb0 = bfp2f(xB[o0]), xb1 = bfp2f(xB[o1]);
        a0 = fmaf(vm0, xa0.x, a0); b0 = fmaf(vm0, xa0.y, b0);
        a1 = fmaf(vm1, xa1.x, a1); b1 = fmaf(vm1, xa1.y, b1);
        c0 = fmaf(v0, xb0.x, c0);  d0 = fmaf(v0, xb0.y, d0);
        c1 = fmaf(v1, xb1.x, c1);  d1 = fmaf(v1, xb1.y, d1);
    }
    if (e < hi) {
        size_t o0 = (size_t)col[e] * 100 + d2;
        float v0 = val[e], vm0 = v0 * emask[e];
        float2 xa0 = bfp2f(xA[o0]);
        float2 xb0 = bfp2f(xB[o0]);
        a0 = fmaf(vm0, xa0.x, a0); b0 = fmaf(vm0, xa0.y, b0);
        c0 = fmaf(v0, xb0.x, c0);  d0 = fmaf(v0, xb0.y, d0);
    }
    float2 oA; oA.x = a0 + a1; oA.y = b0 + b1;
    ((float2*)outA)[(size_t)r * 100 + d2] = oA;
    outB[(size_t)r * 100 + d2] = f2bfp(c0 + c1, d0 + d1);
}

// Final adj pass: out f32 (final x_nd) = sum val * x[col] (x bf16 stride 100)
__global__ __launch_bounds__(256) void spmm_bf32(
    const uint* __restrict__ x, const int* __restrict__ rowptr,
    const int* __restrict__ col, const float* __restrict__ val,
    float* __restrict__ out, int N)
{
    const int sub = threadIdx.x >> 7;
    const int d2  = threadIdx.x & 127;
    const int r   = blockIdx.x * 2 + sub;
    if (d2 >= 100 || r >= N) return;
    const int lo = rowptr[r], hi = rowptr[r + 1];
    float a0 = 0.f, a1 = 0.f, b0 = 0.f, b1 = 0.f;
    int e = lo;
    for (; e + 1 < hi; e += 2) {
        float2 xa = bfp2f(x[(size_t)col[e]     * 100 + d2]);
        float2 xb = bfp2f(x[(size_t)col[e + 1] * 100 + d2]);
        float v0 = val[e], v1 = val[e + 1];
        a0 = fmaf(v0, xa.x, a0); b0 = fmaf(v0, xa.y, b0);
        a1 = fmaf(v1, xb.x, a1); b1 = fmaf(v1, xb.y, b1);
    }
    if (e < hi) {
        float2 xa = bfp2f(x[(size_t)col[e] * 100 + d2]);
        a0 = fmaf(val[e], xa.x, a0); b0 = fmaf(val[e], xa.y, b0);
    }
    float2 o; o.x = a0 + a1; o.y = b0 + b1;
    ((float2*)out)[(size_t)r * 100 + d2] = o;
}

// out(bf16) = m[row]*e0 + (1-m[row])*mp   (e0 f32, mp bf16; elementwise)
__global__ __launch_bounds__(256) void combine_bb(
    const float* __restrict__ e0, const uint* __restrict__ mp,
    const float* __restrict__ mask, uint* __restrict__ out, int N)
{
    int idx = blockIdx.x * 256 + threadIdx.x;   // uint index over N*100
    if (idx >= N * 100) return;
    float m = mask[idx / 100];
    float2 a = ((const float2*)e0)[idx];
    float2 b = bfp2f(mp[idx]);
    out[idx] = f2bfp(fmaf(m, a.x - b.x, b.x), fmaf(m, a.y - b.y, b.y));
}

// self_hr -> bf16 (stride 224, zero-padded)
__global__ __launch_bounds__(256) void selfhr_kernel(
    const float* __restrict__ e0, const float* __restrict__ rel_emb,
    const int* __restrict__ sub, const int* __restrict__ rel,
    ushort* __restrict__ hrbf)
{
    const int b = blockIdx.x;
    __shared__ float lhs[DIMV];
    const int t = threadIdx.x;
    if (t < DIMV) lhs[t] = e0[(size_t)sub[b] * DIMV + t];
    __syncthreads();
    if (t >= 224) return;
    if (t < DIMV) {
        const float* R = rel_emb + (size_t)rel[b] * (DIMV * DIMV);
        float acc = 0.f;
        for (int dd = 0; dd < DIMV; dd++)
            acc = fmaf(lhs[dd], R[dd * DIMV + t], acc);
        hrbf[(size_t)b * 224 + t] = f2bf(acc);
    } else {
        hrbf[(size_t)b * 224 + t] = 0;
    }
}

extern "C" void kernel_launch(void* const* d_in, const int* in_sizes, int n_in,
                              void* d_out, int out_size, void* d_ws, size_t ws_size,
                              hipStream_t stream)
{
    const float* e0       = (const float*)d_in[0];
    const float* rel_emb  = (const float*)d_in[1];
    const float* node_W1  = (const float*)d_in[2];
    const float* node_b1  = (const float*)d_in[3];
    const float* node_W2  = (const float*)d_in[4];
    const float* node_b2  = (const float*)d_in[5];
    const float* edge_W1  = (const float*)d_in[6];
    const float* edge_b1  = (const float*)d_in[7];
    const float* edge_W2  = (const float*)d_in[8];
    const float* edge_b2  = (const float*)d_in[9];
    const int*   adj_row  = (const int*)d_in[10];
    const int*   adj_col  = (const int*)d_in[11];
    const float* adj_val  = (const float*)d_in[12];
    const int*   rw_row   = (const int*)d_in[13];
    const int*   rw_col   = (const int*)d_in[14];
    const float* rw_val   = (const float*)d_in[15];
    const float* node_eps = (const float*)d_in[16];
    const float* edge_eps = (const float*)d_in[17];
    const int*   sub      = (const int*)d_in[18];
    const int*   rel      = (const int*)d_in[19];

    const int E   = in_sizes[10];
    const int Erw = in_sizes[13];
    const int N   = in_sizes[0] / DIMV;   // 50000
    const int B   = in_sizes[18];         // 1024

    // workspace layout (~25.6 MB)
    ushort* W1eT = (ushort*)d_ws;                      // 416*224
    ushort* W1nT = W1eT + 416 * 224;                   // 2*208*224
    ushort* e0bf = W1nT + 2 * 208 * 224;               // N*224
    ushort* hrbf = e0bf + (size_t)N * 224;             // B*224
    float*  fb   = (float*)(hrbf + (size_t)B * 224);
    float*  node_mask = fb;                            // 2*N
    float*  edge_mask = node_mask + 2 * (size_t)N;     // E
    int*    rp_adj = (int*)(edge_mask + E);            // N+1
    int*    rp_rw  = rp_adj + (N + 1);                 // N+1

    // output layout: scores (B*N), x_nd (N*200), x_ed (N*200)
    float* out    = (float*)d_out;
    float* scores = out;
    float* x_nd   = out + (size_t)B * N;
    float* x_ed   = x_nd + (size_t)N * DIMV;
    // scores region (204.8 MB) as scratch until the final GEMM:
    uint*   Tb   = (uint*)scores;                      // N*100 uints (20 MB)
    uint*   T2b  = Tb   + (size_t)N * 100;             // N*100
    uint*   xndb = T2b  + (size_t)N * 100;             // N*100
    uint*   Tnb  = xndb + (size_t)N * 100;             // N*100
    ushort* Pb   = (ushort*)(Tnb + (size_t)N * 100);   // N*400 bf16 (40 MB)

    const int grid2 = (N + 1) / 2;

    // 0. preps
    e0bf_kernel<<<(N * 28 + 255) / 256, 256, 0, stream>>>(e0, e0bf, N);
    transpose_w1e_kernel<<<(416 * 224 + 255) / 256, 256, 0, stream>>>(edge_W1 + 400 * 200, W1eT);
    transpose_w1n_kernel<<<dim3((208 * 224 + 255) / 256, 2), 256, 0, stream>>>(node_W1, W1nT);
    rowptr_kernel<<<(N + 256) / 256, 256, 0, stream>>>(adj_row, E,   N, rp_adj);
    rowptr_kernel<<<(N + 256) / 256, 256, 0, stream>>>(rw_row,  Erw, N, rp_rw);

    // 1. edge path: Pb = bf16(e0 @ [W1a|W1b]) (node-level), then per-edge gate
    gemm_e0_kernel<<<dim3((N + 127) / 128, 2), 256, 0, stream>>>(e0bf, W1eT, Pb, N, 400, 400);
    edge_gate_kernel<<<6144, 256, 0, stream>>>(
        Pb, edge_b1 + 200, edge_W2 + 200, edge_b2 + 1, edge_eps + (size_t)E,
        adj_row, adj_col, edge_mask, E);

    // 2. node masks (both i)
    node_mlp_mfma<<<dim3((N + 127) / 128, 2), 256, 0, stream>>>(
        e0bf, W1nT, node_b1, node_W2, node_b2, node_eps, node_mask, N);

    // 3. shared first rw hop (bf16 in/out): Tb = rw(e0bf)
    spmm_bb<<<grid2, 256, 0, stream>>>((const uint*)e0bf, 112, rp_rw, rw_col, rw_val, Tb, N);

    // 4. edge branch second hop: T2b = rw(Tb)
    spmm_bb<<<grid2, 256, 0, stream>>>(Tb, 100, rp_rw, rw_col, rw_val, T2b, N);

    // 5. node branch step 1 (elementwise): xndb = m0*e0 + (1-m0)*Tb
    combine_bb<<<(N * 100 + 255) / 256, 256, 0, stream>>>(e0, Tb, node_mask, xndb, N);

    // 6. dual adj propagate: x_ed = adj_masked(T2b) [f32 final]; Tnb = adj(xndb)
    spmm_dual_bb<<<grid2, 256, 0, stream>>>(T2b, xndb, rp_adj, adj_col, adj_val,
                                            edge_mask, x_ed, Tnb, N);

    // 7. node branch: T2b = m1*Tnb + (1-m1)*rw(Tnb); x_nd = adj(T2b) [f32 final]
    rw_combine_bb<<<grid2, 256, 0, stream>>>(Tnb, rp_rw, rw_col, rw_val, node_mask + N, T2b, N);
    spmm_bf32<<<grid2, 256, 0, stream>>>(T2b, rp_adj, adj_col, adj_val, x_nd, N);

    // 8. self_hr -> bf16
    selfhr_kernel<<<B, 256, 0, stream>>>(e0, rel_emb, sub, rel, hrbf);

    // 9. scores = sigmoid(self_hr @ e0^T) via MFMA
    scores_mfma<<<dim3((N + 191) / 192, B / 64), 256, 0, stream>>>(hrbf, e0bf, scores, N);
}

// Round 3
// 936.609 us; speedup vs baseline: 1.2369x; 1.0443x over previous
//
#include <hip/hip_runtime.h>
#include <math.h>

#define DIMV 200
typedef unsigned short ushort;
typedef unsigned int uint;
typedef __attribute__((ext_vector_type(8))) __bf16  bf16x8;
typedef __attribute__((ext_vector_type(4))) float   f32x4;

static __device__ __forceinline__ int lower_bound(const int* __restrict__ a, int n, int key) {
    int lo = 0, hi = n;
    while (lo < hi) {
        int mid = (lo + hi) >> 1;
        if (a[mid] < key) lo = mid + 1; else hi = mid;
    }
    return lo;
}

static __device__ __forceinline__ float gate_fn(float u, float logit) {
    // bias = 1e-4: eps = (2b-1)*u + (1-b); sigmoid((log(eps)-log1p(-eps)+logit)/0.5)
    float ee = fmaf(u, -0.9998f, 0.9999f);
    float g  = (logf(ee) - log1pf(-ee) + logit) * 2.0f;
    return 1.0f / (1.0f + expf(-g));
}

static __device__ __forceinline__ ushort f2bf(float f) {
    unsigned int u = __float_as_uint(f);
    return (ushort)((u + 0x7fffu + ((u >> 16) & 1u)) >> 16);
}
// packed pair: low ushort = dim 2k, high ushort = dim 2k+1
static __device__ __forceinline__ float2 bfp2f(uint u) {
    float2 r;
    r.x = __uint_as_float(u << 16);
    r.y = __uint_as_float(u & 0xffff0000u);
    return r;
}
static __device__ __forceinline__ uint f2bfp(float a, float b) {
    return (uint)f2bf(a) | ((uint)f2bf(b) << 16);
}

static __device__ __forceinline__ void cvt8_store(ushort* dst, const float* src) {
    float4 a = *(const float4*)src;
    float4 b = *(const float4*)(src + 4);
    dst[0] = f2bf(a.x); dst[1] = f2bf(a.y); dst[2] = f2bf(a.z); dst[3] = f2bf(a.w);
    dst[4] = f2bf(b.x); dst[5] = f2bf(b.y); dst[6] = f2bf(b.z); dst[7] = f2bf(b.w);
}
static __device__ __forceinline__ void zero8_store(ushort* dst) {
#pragma unroll
    for (int i = 0; i < 8; i++) dst[i] = 0;
}

// ===========================================================================
// K1: prep_all — e0->bf16, both weight transposes, both rowptrs, self_hr.
// Block ranges partition the independent jobs (one launch instead of six).
// ===========================================================================
__global__ __launch_bounds__(256) void prep_all(
    const float* __restrict__ e0, ushort* __restrict__ e0bf,
    const float* __restrict__ w1e_src, ushort* __restrict__ W1eT,
    const float* __restrict__ w1n_src, ushort* __restrict__ W1nT,
    const int* __restrict__ adj_row, int E, int* __restrict__ rp_adj,
    const int* __restrict__ rw_row, int Erw, int* __restrict__ rp_rw,
    const float* __restrict__ rel_emb, const int* __restrict__ sub,
    const int* __restrict__ rel, ushort* __restrict__ hrbf, int N)
{
    __shared__ float lhs[DIMV];
    int bid = blockIdx.x;
    const int t = threadIdx.x;

    const int NB0 = (N * 28 + 255) >> 8;      // e0bf blocks
    if (bid < NB0) {
        int idx = bid * 256 + t;
        if (idx < N * 28) {
            int n = idx / 28, c = idx % 28;
            ushort* dst = e0bf + (size_t)n * 224 + c * 8;
            if (c < 25) cvt8_store(dst, e0 + (size_t)n * 200 + c * 8);
            else        zero8_store(dst);
        }
        return;
    }
    bid -= NB0;
    if (bid < 364) {                          // W1e transpose (416*224)
        int idx = bid * 256 + t;
        if (idx < 416 * 224) {
            int n = idx / 224, k = idx % 224;
            float v = 0.f;
            if (k < 200) {
                if (n < 200)      v = w1e_src[k * 200 + n];
                else if (n < 400) v = w1e_src[(k + 200) * 200 + (n - 200)];
            }
            W1eT[idx] = f2bf(v);
        }
        return;
    }
    bid -= 364;
    if (bid < 364) {                          // W1n transpose, i = bid/182
        int i = bid / 182;
        int idx = (bid % 182) * 256 + t;
        if (idx < 208 * 224) {
            int n = idx / 224, k = idx % 224;
            float v = (n < 200 && k < 200) ? w1n_src[i * 40000 + k * 200 + n] : 0.f;
            W1nT[(size_t)i * 208 * 224 + idx] = f2bf(v);
        }
        return;
    }
    bid -= 364;
    const int NBr = (N + 256) >> 8;           // rowptr blocks
    if (bid < NBr) {
        int r = bid * 256 + t;
        if (r <= N) rp_adj[r] = lower_bound(adj_row, E, r);
        return;
    }
    bid -= NBr;
    if (bid < NBr) {
        int r = bid * 256 + t;
        if (r <= N) rp_rw[r] = lower_bound(rw_row, Erw, r);
        return;
    }
    bid -= NBr;
    // self_hr: one block per batch element
    {
        const int b = bid;
        if (t < DIMV) lhs[t] = e0[(size_t)sub[b] * DIMV + t];
        __syncthreads();
        if (t >= 224) return;
        if (t < DIMV) {
            const float* R = rel_emb + (size_t)rel[b] * (DIMV * DIMV);
            float acc = 0.f;
            for (int dd = 0; dd < DIMV; dd++)
                acc = fmaf(lhs[dd], R[dd * DIMV + t], acc);
            hrbf[(size_t)b * 224 + t] = f2bf(acc);
        } else {
            hrbf[(size_t)b * 224 + t] = 0;
        }
    }
}

// ===========================================================================
// K2: fused MLP GEMM — edge hidden (y=0,1 -> Pb bf16) and node mask MLP
// (y=2,3).  1-D grid, XCD-swizzled so all 4 y-blocks of a given x (sharing
// the same A = e0bf 128-row tile) land on the same XCD's L2.
// ===========================================================================
__global__ __launch_bounds__(256) void fused_mlp(
    const ushort* __restrict__ e0bf, const ushort* __restrict__ W1eT,
    const ushort* __restrict__ W1nT, ushort* __restrict__ Pb,
    const float* __restrict__ nb1, const float* __restrict__ nW2,
    const float* __restrict__ nb2, const float* __restrict__ neps,
    float* __restrict__ node_mask, int N, int GX)
{
    __shared__ __align__(16) ushort As[2][128 * 40];
    __shared__ __align__(16) ushort Bs[2][208 * 40];
    __shared__ float bsh[208], wsh[208];

    const int r8  = blockIdx.x & 7;
    const int rem = blockIdx.x >> 3;
    const int y   = rem & 3;
    const int q4  = rem >> 2;
    const int x   = r8 + 8 * q4;
    if (x >= GX) return;

    const int t    = threadIdx.x;
    const int lane = t & 63;
    const int w    = t >> 6;
    const int q    = lane >> 4;
    const int ln   = lane & 15;
    const int r0   = x * 128;
    const bool edge = (y < 2);
    const int  i    = y - 2;
    const ushort* Wt = edge ? (W1eT + (size_t)y * 208 * 224)
                            : (W1nT + (size_t)i * 208 * 224);

    if (!edge && t < 208) {
        bsh[t] = (t < 200) ? nb1[i * 200 + t] : 0.f;
        wsh[t] = (t < 200) ? nW2[i * 200 + t] : 0.f;
    }

    f32x4 acc[2][13];
#pragma unroll
    for (int mt = 0; mt < 2; mt++)
#pragma unroll
        for (int nt = 0; nt < 13; nt++) {
            acc[mt][nt][0] = 0.f; acc[mt][nt][1] = 0.f;
            acc[mt][nt][2] = 0.f; acc[mt][nt][3] = 0.f;
        }

    auto stageA = [&](int ks, int buf) {
#pragma unroll
        for (int it = 0; it < 2; it++) {
            int f = t + it * 256;
            int m = f >> 2, c4 = f & 3;
            int g = r0 + m;
            ushort* dst = &As[buf][m * 40 + c4 * 8];
            if (g < N) *(bf16x8*)dst = *(const bf16x8*)&e0bf[(size_t)g * 224 + ks * 32 + c4 * 8];
            else       zero8_store(dst);
        }
    };
    auto stageB = [&](int ks, int buf) {
        for (int f = t; f < 832; f += 256) {
            int n = f >> 2, c4 = f & 3;
            *(bf16x8*)&Bs[buf][n * 40 + c4 * 8] =
                *(const bf16x8*)&Wt[(size_t)n * 224 + ks * 32 + c4 * 8];
        }
    };

    stageA(0, 0); stageB(0, 0);
    __syncthreads();

    for (int ks = 0; ks < 7; ks++) {
        int cur = ks & 1;
        if (ks + 1 < 7) { stageA(ks + 1, cur ^ 1); stageB(ks + 1, cur ^ 1); }
        bf16x8 af0 = *(const bf16x8*)&As[cur][(w * 32 + ln) * 40 + q * 8];
        bf16x8 af1 = *(const bf16x8*)&As[cur][(w * 32 + 16 + ln) * 40 + q * 8];
#pragma unroll
        for (int nt = 0; nt < 13; nt++) {
            bf16x8 bf = *(const bf16x8*)&Bs[cur][(nt * 16 + ln) * 40 + q * 8];
            acc[0][nt] = __builtin_amdgcn_mfma_f32_16x16x32_bf16(af0, bf, acc[0][nt], 0, 0, 0);
            acc[1][nt] = __builtin_amdgcn_mfma_f32_16x16x32_bf16(af1, bf, acc[1][nt], 0, 0, 0);
        }
        __syncthreads();
    }

    if (edge) {
#pragma unroll
        for (int mt = 0; mt < 2; mt++) {
            int gm = r0 + w * 32 + mt * 16 + q * 4;
#pragma unroll
            for (int nt = 0; nt < 13; nt++) {
                int gn = y * 208 + nt * 16 + ln;
                if (gn < 400) {
#pragma unroll
                    for (int r = 0; r < 4; r++)
                        if (gm + r < N) Pb[(size_t)(gm + r) * 400 + gn] = f2bf(acc[mt][nt][r]);
                }
            }
        }
    } else {
        float p[2][4];
#pragma unroll
        for (int mt = 0; mt < 2; mt++)
#pragma unroll
            for (int r = 0; r < 4; r++) {
                float s = 0.f;
#pragma unroll
                for (int nt = 0; nt < 13; nt++) {
                    int n = nt * 16 + ln;
                    float h = fmaxf(acc[mt][nt][r] + bsh[n], 0.f);
                    s = fmaf(h, wsh[n], s);
                }
                p[mt][r] = s;
            }
#pragma unroll
        for (int off = 1; off < 16; off <<= 1)
#pragma unroll
            for (int mt = 0; mt < 2; mt++)
#pragma unroll
                for (int r = 0; r < 4; r++)
                    p[mt][r] += __shfl_xor(p[mt][r], off);

        if (ln == 0) {
            float b2v = nb2[i];
            const float* epsi = neps + (size_t)i * N;
            float* outi = node_mask + (size_t)i * N;
#pragma unroll
            for (int mt = 0; mt < 2; mt++)
#pragma unroll
                for (int r = 0; r < 4; r++) {
                    int g = r0 + w * 32 + mt * 16 + q * 4 + r;
                    if (g < N) outi[g] = gate_fn(epsi[g], p[mt][r] + b2v);
                }
        }
    }
}

// ---------------------------------------------------------------------------
// SpMM body (packed bf16 in/out): 2 rows per block, 100 active lanes per row.
// ---------------------------------------------------------------------------
static __device__ __forceinline__ void spmm_bb_body(
    const uint* __restrict__ x, int xld, const int* __restrict__ rowptr,
    const int* __restrict__ col, const float* __restrict__ val,
    uint* __restrict__ out, int N, int bid, int t)
{
    const int sub = t >> 7;
    const int d2  = t & 127;
    const int r   = bid * 2 + sub;
    if (d2 >= 100 || r >= N) return;
    const int lo = rowptr[r], hi = rowptr[r + 1];
    float a0 = 0.f, a1 = 0.f, b0 = 0.f, b1 = 0.f;
    int e = lo;
    for (; e + 1 < hi; e += 2) {
        float2 xa = bfp2f(x[(size_t)col[e]     * xld + d2]);
        float2 xb = bfp2f(x[(size_t)col[e + 1] * xld + d2]);
        float v0 = val[e], v1 = val[e + 1];
        a0 = fmaf(v0, xa.x, a0); b0 = fmaf(v0, xa.y, b0);
        a1 = fmaf(v1, xb.x, a1); b1 = fmaf(v1, xb.y, b1);
    }
    if (e < hi) {
        float2 xa = bfp2f(x[(size_t)col[e] * xld + d2]);
        a0 = fmaf(val[e], xa.x, a0); b0 = fmaf(val[e], xa.y, b0);
    }
    out[(size_t)r * 100 + d2] = f2bfp(a0 + a1, b0 + b1);
}

// ===========================================================================
// K3: Tb = rw(e0bf)  [blocks 0..NB_SP)  +  edge gate [rest].
// Edge gate: wave-per-2-rows (edges row-sorted) — row-half of P loaded ONCE
// per row (bias folded in), col-half gathered per edge as packed uints.
// ===========================================================================
__global__ __launch_bounds__(256) void k3_rw1_egate(
    const uint* __restrict__ e0u, const int* __restrict__ rp_rw,
    const int* __restrict__ rw_col, const float* __restrict__ rw_val,
    uint* __restrict__ Tb,
    const uint* __restrict__ P4, const int* __restrict__ rp_adj,
    const int* __restrict__ adj_col,
    const float* __restrict__ b1, const float* __restrict__ W2,
    const float* __restrict__ b2, const float* __restrict__ eps,
    float* __restrict__ edge_mask, int N, int NB_SP)
{
    int bid = blockIdx.x;
    const int t = threadIdx.x;
    if (bid < NB_SP) {
        spmm_bb_body(e0u, 112, rp_rw, rw_col, rw_val, Tb, N, bid, t);
        return;
    }
    bid -= NB_SP;
    const int lane = t & 63;
    const int w    = t >> 6;
    const int gw   = bid * 4 + w;
    const bool act1 = lane < 36;
    const int dA = 2 * lane;
    const int dB = 128 + 2 * lane;
    const float bb0x = b1[dA], bb0y = b1[dA + 1];
    const float ww0x = W2[dA], ww0y = W2[dA + 1];
    const float bb1x = act1 ? b1[dB] : 0.f, bb1y = act1 ? b1[dB + 1] : 0.f;
    const float ww1x = act1 ? W2[dB] : 0.f, ww1y = act1 ? W2[dB + 1] : 0.f;
    const float b2v = b2[0];

    const int r_lo = gw * 2;
    const int r_hi = min(r_lo + 2, N);
    for (int r = r_lo; r < r_hi; r++) {
        const uint* Pr = P4 + (size_t)r * 200;
        float2 a0 = bfp2f(Pr[lane]);
        float2 a1; a1.x = 0.f; a1.y = 0.f;
        if (act1) a1 = bfp2f(Pr[64 + lane]);
        a0.x += bb0x; a0.y += bb0y; a1.x += bb1x; a1.y += bb1y;
        const int lo = rp_adj[r], hi = rp_adj[r + 1];
        int e = lo;
        for (; e + 1 < hi; e += 2) {
            const uint* Pc0 = P4 + (size_t)adj_col[e]     * 200 + 100;
            const uint* Pc1 = P4 + (size_t)adj_col[e + 1] * 200 + 100;
            float2 q00 = bfp2f(Pc0[lane]);
            float2 q10 = bfp2f(Pc1[lane]);
            float2 q01, q11; q01.x = q01.y = q11.x = q11.y = 0.f;
            if (act1) { q01 = bfp2f(Pc0[64 + lane]); q11 = bfp2f(Pc1[64 + lane]); }
            float s0 = fmaxf(a0.x + q00.x, 0.f) * ww0x + fmaxf(a0.y + q00.y, 0.f) * ww0y
                     + fmaxf(a1.x + q01.x, 0.f) * ww1x + fmaxf(a1.y + q01.y, 0.f) * ww1y;
            float s1 = fmaxf(a0.x + q10.x, 0.f) * ww0x + fmaxf(a0.y + q10.y, 0.f) * ww0y
                     + fmaxf(a1.x + q11.x, 0.f) * ww1x + fmaxf(a1.y + q11.y, 0.f) * ww1y;
#pragma unroll
            for (int off = 32; off; off >>= 1) {
                s0 += __shfl_xor(s0, off);
                s1 += __shfl_xor(s1, off);
            }
            if (lane == 0) {
                edge_mask[e]     = gate_fn(eps[e],     s0 + b2v);
                edge_mask[e + 1] = gate_fn(eps[e + 1], s1 + b2v);
            }
        }
        if (e < hi) {
            const uint* Pc0 = P4 + (size_t)adj_col[e] * 200 + 100;
            float2 q00 = bfp2f(Pc0[lane]);
            float2 q01; q01.x = q01.y = 0.f;
            if (act1) q01 = bfp2f(Pc0[64 + lane]);
            float s0 = fmaxf(a0.x + q00.x, 0.f) * ww0x + fmaxf(a0.y + q00.y, 0.f) * ww0y
                     + fmaxf(a1.x + q01.x, 0.f) * ww1x + fmaxf(a1.y + q01.y, 0.f) * ww1y;
#pragma unroll
            for (int off = 32; off; off >>= 1) s0 += __shfl_xor(s0, off);
            if (lane == 0) edge_mask[e] = gate_fn(eps[e], s0 + b2v);
        }
    }
}

// ===========================================================================
// K4: T2b = rw(Tb) [blocks 0..NB_SP)  +  xndb = m0*e0 + (1-m0)*Tb [rest].
// ===========================================================================
__global__ __launch_bounds__(256) void k4_rw2_combine(
    const uint* __restrict__ Tb, const int* __restrict__ rp_rw,
    const int* __restrict__ rw_col, const float* __restrict__ rw_val,
    uint* __restrict__ T2b,
    const float* __restrict__ e0, const float* __restrict__ mask,
    uint* __restrict__ xndb, int N, int NB_SP)
{
    int bid = blockIdx.x;
    const int t = threadIdx.x;
    if (bid < NB_SP) {
        spmm_bb_body(Tb, 100, rp_rw, rw_col, rw_val, T2b, N, bid, t);
        return;
    }
    bid -= NB_SP;
    int idx = bid * 256 + t;
    if (idx >= N * 100) return;
    float m = mask[idx / 100];
    float2 a = ((const float2*)e0)[idx];
    float2 b = bfp2f(Tb[idx]);
    xndb[idx] = f2bfp(fmaf(m, a.x - b.x, b.x), fmaf(m, a.y - b.y, b.y));
}

// Dual adj pass:
//   outA(f32, final x_ed) = sum val*emask * xA[col]
//   outB(bf16)            = sum val        * xB[col]
__global__ __launch_bounds__(256) void spmm_dual_bb(
    const uint* __restrict__ xA, const uint* __restrict__ xB,
    const int* __restrict__ rowptr, const int* __restrict__ col,
    const float* __restrict__ val, const float* __restrict__ emask,
    float* __restrict__ outA, uint* __restrict__ outB, int N)
{
    const int sub = threadIdx.x >> 7;
    const int d2  = threadIdx.x & 127;
    const int r   = blockIdx.x * 2 + sub;
    if (d2 >= 100 || r >= N) return;
    const int lo = rowptr[r], hi = rowptr[r + 1];
    float a0 = 0.f, a1 = 0.f, b0 = 0.f, b1 = 0.f;
    float c0 = 0.f, c1 = 0.f, d0 = 0.f, d1 = 0.f;
    int e = lo;
    for (; e + 1 < hi; e += 2) {
        size_t o0 = (size_t)col[e]     * 100 + d2;
        size_t o1 = (size_t)col[e + 1] * 100 + d2;
        float v0 = val[e], v1 = val[e + 1];
        float vm0 = v0 * emask[e], vm1 = v1 * emask[e + 1];
        float2 xa0 = bfp2f(xA[o0]), xa1 = bfp2f(xA[o1]);
        float2 xb0 = bfp2f(xB[o0]), xb1 = bfp2f(xB[o1]);
        a0 = fmaf(vm0, xa0.x, a0); b0 = fmaf(vm0, xa0.y, b0);
        a1 = fmaf(vm1, xa1.x, a1); b1 = fmaf(vm1, xa1.y, b1);
        c0 = fmaf(v0, xb0.x, c0);  d0 = fmaf(v0, xb0.y, d0);
        c1 = fmaf(v1, xb1.x, c1);  d1 = fmaf(v1, xb1.y, d1);
    }
    if (e < hi) {
        size_t o0 = (size_t)col[e] * 100 + d2;
        float v0 = val[e], vm0 = v0 * emask[e];
        float2 xa0 = bfp2f(xA[o0]);
        float2 xb0 = bfp2f(xB[o0]);
        a0 = fmaf(vm0, xa0.x, a0); b0 = fmaf(vm0, xa0.y, b0);
        c0 = fmaf(v0, xb0.x, c0);  d0 = fmaf(v0, xb0.y, d0);
    }
    float2 oA; oA.x = a0 + a1; oA.y = b0 + b1;
    ((float2*)outA)[(size_t)r * 100 + d2] = oA;
    outB[(size_t)r * 100 + d2] = f2bfp(c0 + c1, d0 + d1);
}

// out(bf16) = m[r]*x[r] + (1-m[r])*spmm(x)   (x bf16 stride 100)
__global__ __launch_bounds__(256) void rw_combine_bb(
    const uint* __restrict__ x, const int* __restrict__ rowptr,
    const int* __restrict__ col, const float* __restrict__ val,
    const float* __restrict__ mask, uint* __restrict__ out, int N)
{
    const int sub = threadIdx.x >> 7;
    const int d2  = threadIdx.x & 127;
    const int r   = blockIdx.x * 2 + sub;
    if (d2 >= 100 || r >= N) return;
    const int lo = rowptr[r], hi = rowptr[r + 1];
    float a0 = 0.f, a1 = 0.f, b0 = 0.f, b1 = 0.f;
    int e = lo;
    for (; e + 1 < hi; e += 2) {
        float2 xa = bfp2f(x[(size_t)col[e]     * 100 + d2]);
        float2 xb = bfp2f(x[(size_t)col[e + 1] * 100 + d2]);
        float v0 = val[e], v1 = val[e + 1];
        a0 = fmaf(v0, xa.x, a0); b0 = fmaf(v0, xa.y, b0);
        a1 = fmaf(v1, xb.x, a1); b1 = fmaf(v1, xb.y, b1);
    }
    if (e < hi) {
        float2 xa = bfp2f(x[(size_t)col[e] * 100 + d2]);
        a0 = fmaf(val[e], xa.x, a0); b0 = fmaf(val[e], xa.y, b0);
    }
    const float m = mask[r];
    float2 xs = bfp2f(x[(size_t)r * 100 + d2]);
    float sx = a0 + a1, sy = b0 + b1;
    out[(size_t)r * 100 + d2] = f2bfp(fmaf(m, xs.x - sx, sx), fmaf(m, xs.y - sy, sy));
}

// Final adj pass: out f32 (final x_nd) = sum val * x[col] (x bf16 stride 100)
__global__ __launch_bounds__(256) void spmm_bf32(
    const uint* __restrict__ x, const int* __restrict__ rowptr,
    const int* __restrict__ col, const float* __restrict__ val,
    float* __restrict__ out, int N)
{
    const int sub = threadIdx.x >> 7;
    const int d2  = threadIdx.x & 127;
    const int r   = blockIdx.x * 2 + sub;
    if (d2 >= 100 || r >= N) return;
    const int lo = rowptr[r], hi = rowptr[r + 1];
    float a0 = 0.f, a1 = 0.f, b0 = 0.f, b1 = 0.f;
    int e = lo;
    for (; e + 1 < hi; e += 2) {
        float2 xa = bfp2f(x[(size_t)col[e]     * 100 + d2]);
        float2 xb = bfp2f(x[(size_t)col[e + 1] * 100 + d2]);
        float v0 = val[e], v1 = val[e + 1];
        a0 = fmaf(v0, xa.x, a0); b0 = fmaf(v0, xa.y, b0);
        a1 = fmaf(v1, xb.x, a1); b1 = fmaf(v1, xb.y, b1);
    }
    if (e < hi) {
        float2 xa = bfp2f(x[(size_t)col[e] * 100 + d2]);
        a0 = fmaf(val[e], xa.x, a0); b0 = fmaf(val[e], xa.y, b0);
    }
    float2 o; o.x = a0 + a1; o.y = b0 + b1;
    ((float2*)out)[(size_t)r * 100 + d2] = o;
}

// ===========================================================================
// K8: scores = sigmoid(hr @ e0^T).  128 A-rows/block (halves e0bf re-reads),
// A-fragments straight from global (hrbf ~459 KB, L2-resident), XCD swizzle
// so all 8 y-blocks sharing a B-tile land on the same XCD.
// ===========================================================================
__global__ __launch_bounds__(256) void scores_mfma(
    const ushort* __restrict__ hrbf, const ushort* __restrict__ e0bf,
    float* __restrict__ scores, int Nent, int GX)
{
    __shared__ __align__(16) ushort Bs[2][192 * 40];

    const int r8  = blockIdx.x & 7;
    const int rem = blockIdx.x >> 3;
    const int y   = rem & 7;
    const int q8  = rem >> 3;
    const int x   = r8 + 8 * q8;
    if (x >= GX) return;

    const int t    = threadIdx.x;
    const int lane = t & 63;
    const int w    = t >> 6;
    const int q    = lane >> 4;
    const int ln   = lane & 15;
    const int n0   = x * 192;
    const int b0   = y * 128;
    const int arow = b0 + w * 32 + ln;

    auto stageB = [&](int ks, int buf) {
        for (int f = t; f < 768; f += 256) {
            int n = f >> 2, c4 = f & 3;
            int gn = n0 + n;
            ushort* dst = &Bs[buf][n * 40 + c4 * 8];
            if (gn < Nent) *(bf16x8*)dst = *(const bf16x8*)&e0bf[(size_t)gn * 224 + ks * 32 + c4 * 8];
            else           zero8_store(dst);
        }
    };
    stageB(0, 0);

    f32x4 acc[2][12];
#pragma unroll
    for (int mt = 0; mt < 2; mt++)
#pragma unroll
        for (int nt = 0; nt < 12; nt++) {
            acc[mt][nt][0] = 0.f; acc[mt][nt][1] = 0.f;
            acc[mt][nt][2] = 0.f; acc[mt][nt][3] = 0.f;
        }

    bf16x8 a0 = *(const bf16x8*)&hrbf[(size_t)arow * 224 + q * 8];
    bf16x8 a1 = *(const bf16x8*)&hrbf[(size_t)(arow + 16) * 224 + q * 8];
    __syncthreads();

    for (int ks = 0; ks < 7; ks++) {
        int cur = ks & 1;
        bf16x8 a0n = a0, a1n = a1;
        if (ks + 1 < 7) {
            stageB(ks + 1, cur ^ 1);
            a0n = *(const bf16x8*)&hrbf[(size_t)arow * 224 + (ks + 1) * 32 + q * 8];
            a1n = *(const bf16x8*)&hrbf[(size_t)(arow + 16) * 224 + (ks + 1) * 32 + q * 8];
        }
#pragma unroll
        for (int nt = 0; nt < 12; nt++) {
            bf16x8 bf = *(const bf16x8*)&Bs[cur][(nt * 16 + ln) * 40 + q * 8];
            acc[0][nt] = __builtin_amdgcn_mfma_f32_16x16x32_bf16(a0, bf, acc[0][nt], 0, 0, 0);
            acc[1][nt] = __builtin_amdgcn_mfma_f32_16x16x32_bf16(a1, bf, acc[1][nt], 0, 0, 0);
        }
        __syncthreads();
        a0 = a0n; a1 = a1n;
    }

#pragma unroll
    for (int mt = 0; mt < 2; mt++) {
        int b = b0 + w * 32 + mt * 16 + q * 4;
#pragma unroll
        for (int nt = 0; nt < 12; nt++) {
            int n = n0 + nt * 16 + ln;
            if (n < Nent) {
#pragma unroll
                for (int r = 0; r < 4; r++)
                    scores[(size_t)(b + r) * Nent + n] = 1.f / (1.f + __expf(-acc[mt][nt][r]));
            }
        }
    }
}

extern "C" void kernel_launch(void* const* d_in, const int* in_sizes, int n_in,
                              void* d_out, int out_size, void* d_ws, size_t ws_size,
                              hipStream_t stream)
{
    const float* e0       = (const float*)d_in[0];
    const float* rel_emb  = (const float*)d_in[1];
    const float* node_W1  = (const float*)d_in[2];
    const float* node_b1  = (const float*)d_in[3];
    const float* node_W2  = (const float*)d_in[4];
    const float* node_b2  = (const float*)d_in[5];
    const float* edge_W1  = (const float*)d_in[6];
    const float* edge_b1  = (const float*)d_in[7];
    const float* edge_W2  = (const float*)d_in[8];
    const float* edge_b2  = (const float*)d_in[9];
    const int*   adj_row  = (const int*)d_in[10];
    const int*   adj_col  = (const int*)d_in[11];
    const float* adj_val  = (const float*)d_in[12];
    const int*   rw_row   = (const int*)d_in[13];
    const int*   rw_col   = (const int*)d_in[14];
    const float* rw_val   = (const float*)d_in[15];
    const float* node_eps = (const float*)d_in[16];
    const float* edge_eps = (const float*)d_in[17];
    const int*   sub      = (const int*)d_in[18];
    const int*   rel      = (const int*)d_in[19];

    const int E   = in_sizes[10];
    const int Erw = in_sizes[13];
    const int N   = in_sizes[0] / DIMV;   // 50000
    const int B   = in_sizes[18];         // 1024

    // workspace layout (~25.6 MB)
    ushort* W1eT = (ushort*)d_ws;                      // 416*224
    ushort* W1nT = W1eT + 416 * 224;                   // 2*208*224
    ushort* e0bf = W1nT + 2 * 208 * 224;               // N*224
    ushort* hrbf = e0bf + (size_t)N * 224;             // B*224
    float*  fb   = (float*)(hrbf + (size_t)B * 224);
    float*  node_mask = fb;                            // 2*N
    float*  edge_mask = node_mask + 2 * (size_t)N;     // E
    int*    rp_adj = (int*)(edge_mask + E);            // N+1
    int*    rp_rw  = rp_adj + (N + 1);                 // N+1

    // output layout: scores (B*N), x_nd (N*200), x_ed (N*200)
    float* out    = (float*)d_out;
    float* scores = out;
    float* x_nd   = out + (size_t)B * N;
    float* x_ed   = x_nd + (size_t)N * DIMV;
    // scores region (204.8 MB) as scratch until the final GEMM:
    uint*   Tb   = (uint*)scores;                      // N*100 uints (20 MB)
    uint*   T2b  = Tb   + (size_t)N * 100;             // N*100
    uint*   xndb = T2b  + (size_t)N * 100;             // N*100
    uint*   Tnb  = xndb + (size_t)N * 100;             // N*100
    uint*   Pb   = Tnb  + (size_t)N * 100;             // N*200 uints = N*400 bf16

    const int NB_SP = (N + 1) / 2;                     // spmm blocks (2 rows each)
    const int NB0   = (N * 28 + 255) / 256;
    const int NBr   = (N + 256) / 256;
    const int prep_blocks = NB0 + 364 + 364 + NBr + NBr + B;
    const int GXg = (N + 127) / 128;
    const int GXs = (N + 191) / 192;

    // K1: all preps + self_hr
    prep_all<<<prep_blocks, 256, 0, stream>>>(
        e0, e0bf, edge_W1 + 400 * 200, W1eT, node_W1, W1nT,
        adj_row, E, rp_adj, rw_row, Erw, rp_rw,
        rel_emb, sub, rel, hrbf, N);

    // K2: edge hidden GEMM (bf16 Pb) + node mask MLP, XCD-swizzled
    fused_mlp<<<32 * ((GXg + 7) / 8), 256, 0, stream>>>(
        e0bf, W1eT, W1nT, (ushort*)Pb,
        node_b1, node_W2, node_b2, node_eps, node_mask, N, GXg);

    // K3: Tb = rw(e0bf)  +  edge gate (row-grouped, packed loads)
    k3_rw1_egate<<<NB_SP + (NB_SP + 3) / 4, 256, 0, stream>>>(
        (const uint*)e0bf, rp_rw, rw_col, rw_val, Tb,
        Pb, rp_adj, adj_col,
        edge_b1 + 200, edge_W2 + 200, edge_b2 + 1, edge_eps + (size_t)E,
        edge_mask, N, NB_SP);

    // K4: T2b = rw(Tb)  +  xndb = m0*e0 + (1-m0)*Tb
    k4_rw2_combine<<<NB_SP + (N * 100 + 255) / 256, 256, 0, stream>>>(
        Tb, rp_rw, rw_col, rw_val, T2b, e0, node_mask, xndb, N, NB_SP);

    // K5: x_ed = adj_masked(T2b) [f32 final]; Tnb = adj(xndb)
    spmm_dual_bb<<<NB_SP, 256, 0, stream>>>(
        T2b, xndb, rp_adj, adj_col, adj_val, edge_mask, x_ed, Tnb, N);

    // K6: T2b = m1*Tnb + (1-m1)*rw(Tnb)
    rw_combine_bb<<<NB_SP, 256, 0, stream>>>(
        Tnb, rp_rw, rw_col, rw_val, node_mask + N, T2b, N);

    // K7: x_nd = adj(T2b) [f32 final]
    spmm_bf32<<<NB_SP, 256, 0, stream>>>(T2b, rp_adj, adj_col, adj_val, x_nd, N);

    // K8: scores = sigmoid(self_hr @ e0^T)
    scores_mfma<<<64 * ((GXs + 7) / 8), 256, 0, stream>>>(
        hrbf, e0bf, scores, N, GXs);
}